// Round 10
// baseline (449.207 us; speedup 1.0000x reference)
//
#include <hip/hip_runtime.h>
#include <hip/hip_bf16.h>
#include <math.h>

#define BATCH 128
#define NCH 19
#define TLEN 1000
#define NNODES (BATCH * NCH)

// fast ELU: negative branch exp(x)-1 via v_exp_f32.
__device__ __forceinline__ float eluf(float x) { return x > 0.f ? x : __expf(x) - 1.f; }
__device__ __forceinline__ float geluf(float x) { return 0.5f * x * (1.f + erff(x * 0.70710678118654752f)); }
__device__ __forceinline__ float sigf(float x) { return 1.f / (1.f + __expf(-x)); }
__device__ __forceinline__ float lrelu(float x) { return x > 0.f ? x : 0.2f * x; }
// force a wave-uniform float into an SGPR
__device__ __forceinline__ float rfl(float v) {
  return __uint_as_float(__builtin_amdgcn_readfirstlane(__float_as_uint(v)));
}

// ---------------------------------------------------------------------------
// K1a: frontend conv stage for one (b,f) pair. (r1-proven version: x is
// L2-resident so the 16x re-read is cheap; chunked variant was no better)
// grid: B*16 blocks, 256 thr
// ---------------------------------------------------------------------------
__global__ __launch_bounds__(256) void k_pool(
    const float* __restrict__ x, const float* __restrict__ w1,
    const float* __restrict__ bn1g, const float* __restrict__ bn1b,
    const float* __restrict__ dw, const float* __restrict__ bn2g,
    const float* __restrict__ bn2b, float* __restrict__ y4g,
    float* __restrict__ ssum) {
  int blk = blockIdx.x;
  int b = blk >> 4, f = blk & 15;
  int tid = threadIdx.x;
  __shared__ float xw[1024];  // xw[i] = xw_f[i-12], zero-padded
  __shared__ float dws[19], w1s[25];
  __shared__ float redw[4];
  if (tid < 19) dws[tid] = dw[f * 19 + tid];
  else if (tid >= 32 && tid < 57) w1s[tid - 32] = w1[f * 25 + tid - 32];
  __syncthreads();
  const float* xb = x + (size_t)b * NCH * TLEN;
  for (int i = tid; i < 1024; i += 256) {
    int t = i - 12;
    float v = 0.f;
    if (t >= 0 && t < TLEN) {
#pragma unroll
      for (int c = 0; c < 19; c++) v += dws[c] * xb[c * TLEN + t];
    }
    xw[i] = v;
  }
  __syncthreads();
  float g1 = bn1g[f], b1 = bn1b[f];
  float g2 = bn2g[f], b2 = bn2b[f];
  float sumdw = 0.f;
#pragma unroll
  for (int c = 0; c < 19; c++) sumdw += dws[c];
  float scale = g2 * g1, cb = g2 * b1 * sumdw + b2;
  float part = 0.f;
  if (tid < 250) {
    float pool = 0.f;
#pragma unroll
    for (int q = 0; q < 4; q++) {
      int t = 4 * tid + q;
      float acc = 0.f;
#pragma unroll
      for (int k = 0; k < 25; k++) acc += w1s[k] * xw[t + k];
      pool += eluf(scale * acc + cb);
    }
    part = pool;
    y4g[(size_t)(b * 16 + f) * 250 + tid] = pool * 0.25f;
  }
  int lane = tid & 63, wid = tid >> 6;
  for (int off = 32; off > 0; off >>= 1) part += __shfl_down(part, off, 64);
  if (lane == 0) redw[wid] = part;
  __syncthreads();
  if (tid == 0) ssum[b * 16 + f] = redw[0] + redw[1] + redw[2] + redw[3];
}

// ---------------------------------------------------------------------------
// K1b: SE + sep conv (k=16, pad 8) + bn3 + elu + mean -> yv[b,fo]  (r1 ver.)
// ---------------------------------------------------------------------------
__global__ __launch_bounds__(256) void k_sep(
    const float* __restrict__ y4g, const float* __restrict__ ssum,
    const float* __restrict__ sew1, const float* __restrict__ sew2,
    const float* __restrict__ sw, const float* __restrict__ g3,
    const float* __restrict__ b3, float* __restrict__ yv) {
  int blk = blockIdx.x;
  int b = blk >> 4, fo = blk & 15;
  int tid = threadIdx.x;
  __shared__ float yloc[16 * 268];
  __shared__ float sws[256];
  __shared__ float s_s[16], se_s[16], u4[4];
  __shared__ float redw[4];
  sws[tid] = sw[fo * 256 + tid];
  if (tid < 16) s_s[tid] = ssum[b * 16 + tid] * (1.f / 1000.f);
  __syncthreads();
  if (tid < 4) {
    float a = 0.f;
#pragma unroll
    for (int ff = 0; ff < 16; ff++) a += s_s[ff] * sew1[ff * 4 + tid];
    u4[tid] = geluf(a);
  }
  __syncthreads();
  if (tid < 16) {
    float a = 0.f;
#pragma unroll
    for (int j = 0; j < 4; j++) a += u4[j] * sew2[j * 16 + tid];
    se_s[tid] = sigf(a);
  }
  __syncthreads();
#pragma unroll
  for (int fi = 0; fi < 16; fi++) {
    float sc = se_s[fi];
    const float* yr = y4g + (size_t)(b * 16 + fi) * 250;
    for (int j = tid; j < 268; j += 256) {
      float v = (j >= 8 && j < 258) ? yr[j - 8] * sc : 0.f;
      yloc[fi * 268 + j] = v;
    }
  }
  __syncthreads();
  float accsum = 0.f;
  if (tid < 251) {
    float acc = 0.f;
#pragma unroll
    for (int fi = 0; fi < 16; fi++) {
      const float* yr = &yloc[fi * 268 + tid];
      const float* wp = &sws[fi * 16];
#pragma unroll
      for (int k = 0; k < 16; k++) acc += yr[k] * wp[k];
    }
    accsum = eluf(g3[fo] * acc + b3[fo]);
  }
  int lane = tid & 63, wid = tid >> 6;
  for (int off = 32; off > 0; off >>= 1)
    accsum += __shfl_down(accsum, off, 64);
  if (lane == 0) redw[wid] = accsum;
  __syncthreads();
  if (tid == 0)
    yv[b * 16 + fo] = (redw[0] + redw[1] + redw[2] + redw[3]) * (1.f / 251.f);
}

// ---------------------------------------------------------------------------
// K2: multiscale conv1d, wave-per-filter + SGPR weights, DOUBLE-WINDOW:
// both t-windows (t0 and t0+512) loaded into registers up front (22 b128),
// then 1200 FMAs run from registers -- LDS latency amortized/overlapped by
// the compiler's counted lgkmcnt. A-half unguarded (t0<=504); B-half uses
// one whole-lane predicate (lane<=60), clamped load base.
// grid: NNODES blocks, 256 thr (4 waves).
// ---------------------------------------------------------------------------
#define PHYS(i) ((i) + ((((i) >> 5)) << 2))
__global__ __launch_bounds__(256) void k_ms(
    const float* __restrict__ x, const float* __restrict__ w0,
    const float* __restrict__ ga0, const float* __restrict__ bb0,
    const float* __restrict__ w1, const float* __restrict__ ga1,
    const float* __restrict__ bb1, const float* __restrict__ w2,
    const float* __restrict__ ga2, const float* __restrict__ bb2,
    const float* __restrict__ yv, float* __restrict__ feat) {
  int n = blockIdx.x, tid = threadIdx.x;
  int lane = tid & 63, wid = tid >> 6;
  __shared__ __align__(16) float xr[1172];  // PHYS layout; logical i = x[n,i-17]
  __shared__ float red_s[16];
  for (int i = tid; i < 1040; i += 256) {
    int t = i - 17;
    xr[PHYS(i)] = (t >= 0 && t < TLEN) ? x[(size_t)n * TLEN + t] : 0.f;
  }
  __syncthreads();

  int t0 = 8 * lane;           // 0..504: A-half always fully valid
  int tB = t0 + 512;           // 512..1016
  bool validB = (tB <= 992);   // lane <= 60: all 8 B-outputs valid
  int rbB = validB ? tB : 992; // clamp load base for masked lanes

#pragma unroll 1
  for (int fg = 0; fg < 4; fg++) {
    int fu = __builtin_amdgcn_readfirstlane(wid * 4 + fg);
    // weights wave-uniform -> SGPR via rfl(value)
    float wa[15], wb[25], wc[35];
#pragma unroll
    for (int k = 0; k < 15; k++) wa[k] = rfl(w0[fu * 15 + k]);
#pragma unroll
    for (int k = 0; k < 25; k++) wb[k] = rfl(w1[fu * 25 + k]);
#pragma unroll
    for (int k = 0; k < 35; k++) wc[k] = rfl(w2[fu * 35 + k]);
    float g0 = rfl(ga0[fu]), c0 = rfl(bb0[fu]);
    float g1 = rfl(ga1[fu]), c1 = rfl(bb1[fu]);
    float g2 = rfl(ga2[fu]), c2 = rfl(bb2[fu]);

    // both windows up front: 22 x ds_read_b128
    float xvA[44], xvB[44];
#pragma unroll
    for (int j = 0; j < 11; j++) {
      float4 qa = *reinterpret_cast<const float4*>(&xr[PHYS(t0 + 4 * j)]);
      float4 qb = *reinterpret_cast<const float4*>(&xr[PHYS(rbB + 4 * j)]);
      xvA[4 * j] = qa.x; xvA[4 * j + 1] = qa.y;
      xvA[4 * j + 2] = qa.z; xvA[4 * j + 3] = qa.w;
      xvB[4 * j] = qb.x; xvB[4 * j + 1] = qb.y;
      xvB[4 * j + 2] = qb.z; xvB[4 * j + 3] = qb.w;
    }

    float z = 0.f, zB = 0.f;
#pragma unroll
    for (int q = 0; q < 8; q++) {
      float a0 = 0.f, a1 = 0.f, a2 = 0.f;
      float b0 = 0.f, b1 = 0.f, b2 = 0.f;
#pragma unroll
      for (int k = 0; k < 15; k++) {
        a0 += xvA[q + 10 + k] * wa[k];
        b0 += xvB[q + 10 + k] * wa[k];
      }
#pragma unroll
      for (int k = 0; k < 25; k++) {
        a1 += xvA[q + 5 + k] * wb[k];
        b1 += xvB[q + 5 + k] * wb[k];
      }
#pragma unroll
      for (int k = 0; k < 35; k++) {
        a2 += xvA[q + k] * wc[k];
        b2 += xvB[q + k] * wc[k];
      }
      z += eluf(g0 * a0 + c0) + eluf(g1 * a1 + c1) + eluf(g2 * a2 + c2);
      zB += eluf(g0 * b0 + c0) + eluf(g1 * b1 + c1) + eluf(g2 * b2 + c2);
    }
    z += validB ? zB : 0.f;

    for (int off = 32; off > 0; off >>= 1) z += __shfl_down(z, off, 64);
    if (lane == 0) red_s[fu] = z;
  }
  __syncthreads();
  if (tid < 16) {
    feat[(size_t)n * 32 + 16 + tid] = red_s[tid] * (1.f / 3000.f);
    feat[(size_t)n * 32 + tid] = yv[(n / 19) * 16 + tid];
  }
}

// ---------------------------------------------------------------------------
// K3: fused GAT1 + GAT2 + pool + classifier. One block per batch element.
// grid: B blocks, 256 thr.  (unchanged)
// ---------------------------------------------------------------------------
__global__ __launch_bounds__(256) void k_gat(
    const float* __restrict__ feat, const float* __restrict__ adjw,
    const float* __restrict__ adjb, const float* __restrict__ g1w,
    const float* __restrict__ g1as, const float* __restrict__ g1ad,
    const float* __restrict__ g1bias, const float* __restrict__ skw,
    const float* __restrict__ skb, const float* __restrict__ bg1,
    const float* __restrict__ bb1, const float* __restrict__ g2w,
    const float* __restrict__ g2as, const float* __restrict__ g2ad,
    const float* __restrict__ g2bias, const float* __restrict__ bg2,
    const float* __restrict__ bb2, const float* __restrict__ cw1,
    const float* __restrict__ cb1, const float* __restrict__ cw2,
    const float* __restrict__ cb2, float* __restrict__ out) {
  int b = blockIdx.x, tid = threadIdx.x;
  __shared__ float fb[19 * 32];
  __shared__ float h1[19 * 512];  // reused for h2
  __shared__ float as_s[19 * 8], ad_s[19 * 8], sc_s[19];
  __shared__ float watt[19 * 8 * 19];
  __shared__ float hb[19 * 64];   // gat1 output / gat2 input
  __shared__ float hout[19 * 64];
  __shared__ float gpool[64], u_s[64];

  for (int i = tid; i < 19 * 32; i += 256) fb[i] = feat[(size_t)b * 19 * 32 + i];
  __syncthreads();

  // ---- h1 = fb(19x32) @ g1w(32x512): thread owns columns tid, tid+256 ----
  {
    float wc0[32], wc1[32];
#pragma unroll
    for (int c = 0; c < 32; c++) {
      wc0[c] = g1w[c * 512 + tid];
      wc1[c] = g1w[c * 512 + tid + 256];
    }
    for (int i = 0; i < 19; i++) {
      float frow[32];
#pragma unroll
      for (int c = 0; c < 32; c++) frow[c] = fb[i * 32 + c];
      float a0 = 0.f, a1 = 0.f;
#pragma unroll
      for (int c = 0; c < 32; c++) {
        a0 += frow[c] * wc0[c];
        a1 += frow[c] * wc1[c];
      }
      h1[i * 512 + tid] = a0;
      h1[i * 512 + tid + 256] = a1;
    }
  }
  // adjacency scores
  if (tid < 19) {
    float a = adjb[0];
#pragma unroll
    for (int c = 0; c < 32; c++) a += fb[tid * 32 + c] * adjw[c];
    sc_s[tid] = sigf(a);
  }
  __syncthreads();

  // ---- gat1 attention ----
  if (tid < 152) {
    int i = tid / 8, h = tid & 7;
    float a = 0.f, d2 = 0.f;
#pragma unroll
    for (int d = 0; d < 64; d++) {
      float hv = h1[i * 512 + h * 64 + d];
      a += hv * g1as[h * 64 + d];
      d2 += hv * g1ad[h * 64 + d];
    }
    as_s[tid] = a;
    ad_s[tid] = d2;
  }
  __syncthreads();
  if (tid < 152) {
    int j = tid / 8, h = tid & 7;
    float adj_ = ad_s[j * 8 + h];
    float ev[19], m = -1e30f;
#pragma unroll
    for (int i = 0; i < 19; i++) {
      float e = lrelu(as_s[i * 8 + h] + adj_);
      ev[i] = e;
      m = fmaxf(m, e);
    }
    float den = 0.f;
#pragma unroll
    for (int i = 0; i < 19; i++) {
      ev[i] = __expf(ev[i] - m);
      den += ev[i];
    }
    float inv = 1.f / (den + 1e-16f);
    float scj = sc_s[j];
#pragma unroll
    for (int i = 0; i < 19; i++)
      watt[(j * 8 + h) * 19 + i] = ev[i] * inv * sc_s[i] * scj;
  }
  __syncthreads();
  // ---- gat1 aggregate + bn + skip + gelu -> hb ----
  for (int idx = tid; idx < 19 * 64; idx += 256) {
    int j = idx >> 6, d = idx & 63;
    float acc = 0.f;
#pragma unroll
    for (int h = 0; h < 8; h++) {
      const float* wr = &watt[(j * 8 + h) * 19];
      float a = 0.f;
#pragma unroll
      for (int i = 0; i < 19; i++) a += wr[i] * h1[i * 512 + h * 64 + d];
      acc += a;
    }
    float om = acc * 0.125f + g1bias[d];
    float v = bg1[d] * om + bb1[d];
    float sk = skb[d];
    const float* fr = &fb[j * 32];
#pragma unroll
    for (int c = 0; c < 32; c++) sk += fr[c] * skw[c * 64 + d];
    hb[idx] = geluf(v + sk);
  }
  __syncthreads();

  // ---- h2 = hb(19x64) @ g2w(64x512), overwrite h1 buffer ----
#pragma unroll
  for (int oo = 0; oo < 2; oo++) {
    int o = tid + oo * 256;
    float wc[64];
#pragma unroll
    for (int c = 0; c < 64; c++) wc[c] = g2w[c * 512 + o];
    for (int i = 0; i < 19; i++) {
      float a = 0.f;
#pragma unroll
      for (int c = 0; c < 64; c++) a += hb[i * 64 + c] * wc[c];
      h1[i * 512 + o] = a;
    }
  }
  __syncthreads();

  // ---- gat2 attention ----
  if (tid < 152) {
    int i = tid / 8, h = tid & 7;
    float a = 0.f, d2 = 0.f;
#pragma unroll
    for (int d = 0; d < 64; d++) {
      float hv = h1[i * 512 + h * 64 + d];
      a += hv * g2as[h * 64 + d];
      d2 += hv * g2ad[h * 64 + d];
    }
    as_s[tid] = a;
    ad_s[tid] = d2;
  }
  __syncthreads();
  if (tid < 152) {
    int j = tid / 8, h = tid & 7;
    float adj_ = ad_s[j * 8 + h];
    float ev[19], m = -1e30f;
#pragma unroll
    for (int i = 0; i < 19; i++) {
      float e = lrelu(as_s[i * 8 + h] + adj_);
      ev[i] = e;
      m = fmaxf(m, e);
    }
    float den = 0.f;
#pragma unroll
    for (int i = 0; i < 19; i++) {
      ev[i] = __expf(ev[i] - m);
      den += ev[i];
    }
    float inv = 1.f / (den + 1e-16f);
    float scj = sc_s[j];
#pragma unroll
    for (int i = 0; i < 19; i++)
      watt[(j * 8 + h) * 19 + i] = ev[i] * inv * sc_s[i] * scj;
  }
  __syncthreads();
  // ---- gat2 aggregate + bn + residual + gelu -> hout ----
  for (int idx = tid; idx < 19 * 64; idx += 256) {
    int j = idx >> 6, d = idx & 63;
    float acc = 0.f;
#pragma unroll
    for (int h = 0; h < 8; h++) {
      const float* wr = &watt[(j * 8 + h) * 19];
      float a = 0.f;
#pragma unroll
      for (int i = 0; i < 19; i++) a += wr[i] * h1[i * 512 + h * 64 + d];
      acc += a;
    }
    float om = acc * 0.125f + g2bias[d];
    float v = bg2[d] * om + bb2[d] + om;
    hout[idx] = geluf(v);
  }
  __syncthreads();

  // ---- pool + classifier ----
  if (tid < 64) {
    float a = 0.f;
#pragma unroll
    for (int j = 0; j < 19; j++) a += hout[j * 64 + tid];
    gpool[tid] = a * (1.f / 19.f);
  }
  __syncthreads();
  if (tid < 64) {
    float a = cb1[tid];
#pragma unroll
    for (int d = 0; d < 64; d++) a += gpool[d] * cw1[d * 64 + tid];
    u_s[tid] = geluf(a);
  }
  __syncthreads();
  if (tid < 2) {
    float a = cb2[tid];
#pragma unroll
    for (int e = 0; e < 64; e++) a += u_s[e] * cw2[e * 2 + tid];
    out[b * 2 + tid] = a;
  }
}

// ---------------------------------------------------------------------------
extern "C" void kernel_launch(void* const* d_in, const int* in_sizes, int n_in,
                              void* d_out, int out_size, void* d_ws,
                              size_t ws_size, hipStream_t stream) {
  (void)in_sizes; (void)n_in; (void)out_size; (void)ws_size;
  const float* x = (const float*)d_in[0];
  const float* conv1_w = (const float*)d_in[1];
  const float* bn1_g = (const float*)d_in[2];
  const float* bn1_b = (const float*)d_in[3];
  const float* depth_w = (const float*)d_in[4];
  const float* bn2_g = (const float*)d_in[5];
  const float* bn2_b = (const float*)d_in[6];
  const float* se_w1 = (const float*)d_in[7];
  const float* se_w2 = (const float*)d_in[8];
  const float* sep_w = (const float*)d_in[9];
  const float* bn3_g = (const float*)d_in[10];
  const float* bn3_b = (const float*)d_in[11];
  const float* ms_w0 = (const float*)d_in[12];
  const float* ms_g0 = (const float*)d_in[13];
  const float* ms_b0 = (const float*)d_in[14];
  const float* ms_w1 = (const float*)d_in[15];
  const float* ms_g1 = (const float*)d_in[16];
  const float* ms_b1 = (const float*)d_in[17];
  const float* ms_w2 = (const float*)d_in[18];
  const float* ms_g2 = (const float*)d_in[19];
  const float* ms_b2 = (const float*)d_in[20];
  const float* adj_w = (const float*)d_in[21];
  const float* adj_b = (const float*)d_in[22];
  const float* gat1_w = (const float*)d_in[23];
  const float* gat1_as = (const float*)d_in[24];
  const float* gat1_ad = (const float*)d_in[25];
  const float* gat1_bias = (const float*)d_in[26];
  const float* skip1_w = (const float*)d_in[27];
  const float* skip1_b = (const float*)d_in[28];
  const float* bng1_g = (const float*)d_in[29];
  const float* bng1_b = (const float*)d_in[30];
  const float* gat2_w = (const float*)d_in[31];
  const float* gat2_as = (const float*)d_in[32];
  const float* gat2_ad = (const float*)d_in[33];
  const float* gat2_bias = (const float*)d_in[34];
  const float* bng2_g = (const float*)d_in[35];
  const float* bng2_b = (const float*)d_in[36];
  const float* cls_w1 = (const float*)d_in[37];
  const float* cls_b1 = (const float*)d_in[38];
  const float* cls_w2 = (const float*)d_in[39];
  const float* cls_b2 = (const float*)d_in[40];
  // d_in[41] edge_index / d_in[42] batch_idx: fixed dense structure, unused

  float* ws = (float*)d_ws;
  float* yv = ws;                  // 2,048
  float* feat = ws + 2048;         // 77,824
  float* y4g = ws + 79872;         // 512,000
  float* ssum = ws + 591872;       // 2,048  -> total ~2.3 MB

  hipLaunchKernelGGL(k_pool, dim3(BATCH * 16), dim3(256), 0, stream,
                     x, conv1_w, bn1_g, bn1_b, depth_w, bn2_g, bn2_b, y4g, ssum);
  hipLaunchKernelGGL(k_sep, dim3(BATCH * 16), dim3(256), 0, stream,
                     y4g, ssum, se_w1, se_w2, sep_w, bn3_g, bn3_b, yv);
  hipLaunchKernelGGL(k_ms, dim3(NNODES), dim3(256), 0, stream,
                     x, ms_w0, ms_g0, ms_b0, ms_w1, ms_g1, ms_b1, ms_w2,
                     ms_g2, ms_b2, yv, feat);
  hipLaunchKernelGGL(k_gat, dim3(BATCH), dim3(256), 0, stream,
                     feat, adj_w, adj_b, gat1_w, gat1_as, gat1_ad, gat1_bias,
                     skip1_w, skip1_b, bng1_g, bng1_b, gat2_w, gat2_as,
                     gat2_ad, gat2_bias, bng2_g, bng2_b, cls_w1, cls_b1,
                     cls_w2, cls_b2, (float*)d_out);
}

// Round 11
// 345.437 us; speedup vs baseline: 1.3004x; 1.3004x over previous
//
#include <hip/hip_runtime.h>
#include <hip/hip_bf16.h>
#include <math.h>

#define BATCH 128
#define NCH 19
#define TLEN 1000
#define NNODES (BATCH * NCH)

// fast ELU (k_pool/k_sep/k_gat): negative branch via v_exp_f32.
__device__ __forceinline__ float eluf(float x) { return x > 0.f ? x : __expf(x) - 1.f; }
// r0-exact ELU (k_ms ONLY): expm1f's register pressure shapes the proven
// 80-VGPR schedule; every "cheaper" variant regressed via regalloc.
__device__ __forceinline__ float elu0(float x) { return x > 0.f ? x : expm1f(x); }
__device__ __forceinline__ float geluf(float x) { return 0.5f * x * (1.f + erff(x * 0.70710678118654752f)); }
__device__ __forceinline__ float sigf(float x) { return 1.f / (1.f + __expf(-x)); }
__device__ __forceinline__ float lrelu(float x) { return x > 0.f ? x : 0.2f * x; }

// ---------------------------------------------------------------------------
// K1a: frontend conv stage for one (b,f) pair. (r1-proven)
// grid: B*16 blocks, 256 thr
// ---------------------------------------------------------------------------
__global__ __launch_bounds__(256) void k_pool(
    const float* __restrict__ x, const float* __restrict__ w1,
    const float* __restrict__ bn1g, const float* __restrict__ bn1b,
    const float* __restrict__ dw, const float* __restrict__ bn2g,
    const float* __restrict__ bn2b, float* __restrict__ y4g,
    float* __restrict__ ssum) {
  int blk = blockIdx.x;
  int b = blk >> 4, f = blk & 15;
  int tid = threadIdx.x;
  __shared__ float xw[1024];  // xw[i] = xw_f[i-12], zero-padded
  __shared__ float dws[19], w1s[25];
  __shared__ float redw[4];
  if (tid < 19) dws[tid] = dw[f * 19 + tid];
  else if (tid >= 32 && tid < 57) w1s[tid - 32] = w1[f * 25 + tid - 32];
  __syncthreads();
  const float* xb = x + (size_t)b * NCH * TLEN;
  for (int i = tid; i < 1024; i += 256) {
    int t = i - 12;
    float v = 0.f;
    if (t >= 0 && t < TLEN) {
#pragma unroll
      for (int c = 0; c < 19; c++) v += dws[c] * xb[c * TLEN + t];
    }
    xw[i] = v;
  }
  __syncthreads();
  float g1 = bn1g[f], b1 = bn1b[f];
  float g2 = bn2g[f], b2 = bn2b[f];
  float sumdw = 0.f;
#pragma unroll
  for (int c = 0; c < 19; c++) sumdw += dws[c];
  float scale = g2 * g1, cb = g2 * b1 * sumdw + b2;
  float part = 0.f;
  if (tid < 250) {
    float pool = 0.f;
#pragma unroll
    for (int q = 0; q < 4; q++) {
      int t = 4 * tid + q;
      float acc = 0.f;
#pragma unroll
      for (int k = 0; k < 25; k++) acc += w1s[k] * xw[t + k];
      pool += eluf(scale * acc + cb);
    }
    part = pool;
    y4g[(size_t)(b * 16 + f) * 250 + tid] = pool * 0.25f;
  }
  int lane = tid & 63, wid = tid >> 6;
  for (int off = 32; off > 0; off >>= 1) part += __shfl_down(part, off, 64);
  if (lane == 0) redw[wid] = part;
  __syncthreads();
  if (tid == 0) ssum[b * 16 + f] = redw[0] + redw[1] + redw[2] + redw[3];
}

// ---------------------------------------------------------------------------
// K1b: SE + sep conv (k=16, pad 8) + bn3 + elu + mean -> yv[b,fo] (r1-proven)
// ---------------------------------------------------------------------------
__global__ __launch_bounds__(256) void k_sep(
    const float* __restrict__ y4g, const float* __restrict__ ssum,
    const float* __restrict__ sew1, const float* __restrict__ sew2,
    const float* __restrict__ sw, const float* __restrict__ g3,
    const float* __restrict__ b3, float* __restrict__ yv) {
  int blk = blockIdx.x;
  int b = blk >> 4, fo = blk & 15;
  int tid = threadIdx.x;
  __shared__ float yloc[16 * 268];
  __shared__ float sws[256];
  __shared__ float s_s[16], se_s[16], u4[4];
  __shared__ float redw[4];
  sws[tid] = sw[fo * 256 + tid];
  if (tid < 16) s_s[tid] = ssum[b * 16 + tid] * (1.f / 1000.f);
  __syncthreads();
  if (tid < 4) {
    float a = 0.f;
#pragma unroll
    for (int ff = 0; ff < 16; ff++) a += s_s[ff] * sew1[ff * 4 + tid];
    u4[tid] = geluf(a);
  }
  __syncthreads();
  if (tid < 16) {
    float a = 0.f;
#pragma unroll
    for (int j = 0; j < 4; j++) a += u4[j] * sew2[j * 16 + tid];
    se_s[tid] = sigf(a);
  }
  __syncthreads();
#pragma unroll
  for (int fi = 0; fi < 16; fi++) {
    float sc = se_s[fi];
    const float* yr = y4g + (size_t)(b * 16 + fi) * 250;
    for (int j = tid; j < 268; j += 256) {
      float v = (j >= 8 && j < 258) ? yr[j - 8] * sc : 0.f;
      yloc[fi * 268 + j] = v;
    }
  }
  __syncthreads();
  float accsum = 0.f;
  if (tid < 251) {
    float acc = 0.f;
#pragma unroll
    for (int fi = 0; fi < 16; fi++) {
      const float* yr = &yloc[fi * 268 + tid];
      const float* wp = &sws[fi * 16];
#pragma unroll
      for (int k = 0; k < 16; k++) acc += yr[k] * wp[k];
    }
    accsum = eluf(g3[fo] * acc + b3[fo]);
  }
  int lane = tid & 63, wid = tid >> 6;
  for (int off = 32; off > 0; off >>= 1)
    accsum += __shfl_down(accsum, off, 64);
  if (lane == 0) redw[wid] = accsum;
  __syncthreads();
  if (tid == 0)
    yv[b * 16 + fo] = (redw[0] + redw[1] + redw[2] + redw[3]) * (1.f / 251.f);
}

// ---------------------------------------------------------------------------
// K2: multiscale conv1d — ROUND-0 EXACT (measured 143 us, VGPR 80, 0 bank
// conflicts). One filter per lane (f=tid&15: LDS broadcast window reads),
// 16 p-planes x 8 outputs/iter from a shared register window; weights from
// LDS once; expm1f ELU (elu0). Ten rounds of restructuring never beat this.
// grid: NNODES blocks, 256 thr.
// ---------------------------------------------------------------------------
#define RP 8
__global__ __launch_bounds__(256) void k_ms(
    const float* __restrict__ x, const float* __restrict__ w0,
    const float* __restrict__ ga0, const float* __restrict__ bb0,
    const float* __restrict__ w1, const float* __restrict__ ga1,
    const float* __restrict__ bb1, const float* __restrict__ w2,
    const float* __restrict__ ga2, const float* __restrict__ bb2,
    const float* __restrict__ yv, float* __restrict__ feat) {
  int n = blockIdx.x, tid = threadIdx.x;
  __shared__ float xr[1034];   // xr[i] = x[n, i-17], zero padded
  __shared__ float wst[1200];  // w0(240) | w1(400) | w2(560)
  __shared__ float red[256];
  for (int i = tid; i < 1034; i += 256) {
    int t = i - 17;
    xr[i] = (t >= 0 && t < TLEN) ? x[(size_t)n * TLEN + t] : 0.f;
  }
  for (int i = tid; i < 240; i += 256) wst[i] = w0[i];
  for (int i = tid; i < 400; i += 256) wst[240 + i] = w1[i];
  for (int i = tid; i < 560; i += 256) wst[640 + i] = w2[i];
  __syncthreads();

  int f = tid & 15, plane = tid >> 4;
  float wa[15], wb[25], wc[35];
#pragma unroll
  for (int k = 0; k < 15; k++) wa[k] = wst[f * 15 + k];
#pragma unroll
  for (int k = 0; k < 25; k++) wb[k] = wst[240 + f * 25 + k];
#pragma unroll
  for (int k = 0; k < 35; k++) wc[k] = wst[640 + f * 35 + k];
  float g0 = ga0[f], c0 = bb0[f];
  float g1 = ga1[f], c1 = bb1[f];
  float g2 = ga2[f], c2 = bb2[f];

  float z = 0.f;
  for (int base = plane * RP; base < TLEN; base += 16 * RP) {
    float xv[34 + RP];
#pragma unroll
    for (int i = 0; i < 34 + RP; i++) xv[i] = xr[base + i];
#pragma unroll
    for (int r = 0; r < RP; r++) {
      float a0 = 0.f, a1 = 0.f, a2 = 0.f;
#pragma unroll
      for (int k = 0; k < 15; k++) a0 += xv[r + 10 + k] * wa[k];
#pragma unroll
      for (int k = 0; k < 25; k++) a1 += xv[r + 5 + k] * wb[k];
#pragma unroll
      for (int k = 0; k < 35; k++) a2 += xv[r + k] * wc[k];
      z += elu0(g0 * a0 + c0) + elu0(g1 * a1 + c1) + elu0(g2 * a2 + c2);
    }
  }
  red[tid] = z;
  __syncthreads();
  for (int s = 128; s >= 16; s >>= 1) {
    if (tid < s) red[tid] += red[tid + s];
    __syncthreads();
  }
  if (tid < 16) {
    feat[(size_t)n * 32 + 16 + tid] = red[tid] * (1.f / 3000.f);
    feat[(size_t)n * 32 + tid] = yv[(n / 19) * 16 + tid];
  }
}

// ---------------------------------------------------------------------------
// K3: fused GAT1 + GAT2 + pool + classifier. (r1-proven)
// grid: B blocks, 256 thr.
// ---------------------------------------------------------------------------
__global__ __launch_bounds__(256) void k_gat(
    const float* __restrict__ feat, const float* __restrict__ adjw,
    const float* __restrict__ adjb, const float* __restrict__ g1w,
    const float* __restrict__ g1as, const float* __restrict__ g1ad,
    const float* __restrict__ g1bias, const float* __restrict__ skw,
    const float* __restrict__ skb, const float* __restrict__ bg1,
    const float* __restrict__ bb1, const float* __restrict__ g2w,
    const float* __restrict__ g2as, const float* __restrict__ g2ad,
    const float* __restrict__ g2bias, const float* __restrict__ bg2,
    const float* __restrict__ bb2, const float* __restrict__ cw1,
    const float* __restrict__ cb1, const float* __restrict__ cw2,
    const float* __restrict__ cb2, float* __restrict__ out) {
  int b = blockIdx.x, tid = threadIdx.x;
  __shared__ float fb[19 * 32];
  __shared__ float h1[19 * 512];  // reused for h2
  __shared__ float as_s[19 * 8], ad_s[19 * 8], sc_s[19];
  __shared__ float watt[19 * 8 * 19];
  __shared__ float hb[19 * 64];   // gat1 output / gat2 input
  __shared__ float hout[19 * 64];
  __shared__ float gpool[64], u_s[64];

  for (int i = tid; i < 19 * 32; i += 256) fb[i] = feat[(size_t)b * 19 * 32 + i];
  __syncthreads();

  // ---- h1 = fb(19x32) @ g1w(32x512): thread owns columns tid, tid+256 ----
  {
    float wc0[32], wc1[32];
#pragma unroll
    for (int c = 0; c < 32; c++) {
      wc0[c] = g1w[c * 512 + tid];
      wc1[c] = g1w[c * 512 + tid + 256];
    }
    for (int i = 0; i < 19; i++) {
      float frow[32];
#pragma unroll
      for (int c = 0; c < 32; c++) frow[c] = fb[i * 32 + c];
      float a0 = 0.f, a1 = 0.f;
#pragma unroll
      for (int c = 0; c < 32; c++) {
        a0 += frow[c] * wc0[c];
        a1 += frow[c] * wc1[c];
      }
      h1[i * 512 + tid] = a0;
      h1[i * 512 + tid + 256] = a1;
    }
  }
  // adjacency scores
  if (tid < 19) {
    float a = adjb[0];
#pragma unroll
    for (int c = 0; c < 32; c++) a += fb[tid * 32 + c] * adjw[c];
    sc_s[tid] = sigf(a);
  }
  __syncthreads();

  // ---- gat1 attention ----
  if (tid < 152) {
    int i = tid / 8, h = tid & 7;
    float a = 0.f, d2 = 0.f;
#pragma unroll
    for (int d = 0; d < 64; d++) {
      float hv = h1[i * 512 + h * 64 + d];
      a += hv * g1as[h * 64 + d];
      d2 += hv * g1ad[h * 64 + d];
    }
    as_s[tid] = a;
    ad_s[tid] = d2;
  }
  __syncthreads();
  if (tid < 152) {
    int j = tid / 8, h = tid & 7;
    float adj_ = ad_s[j * 8 + h];
    float ev[19], m = -1e30f;
#pragma unroll
    for (int i = 0; i < 19; i++) {
      float e = lrelu(as_s[i * 8 + h] + adj_);
      ev[i] = e;
      m = fmaxf(m, e);
    }
    float den = 0.f;
#pragma unroll
    for (int i = 0; i < 19; i++) {
      ev[i] = __expf(ev[i] - m);
      den += ev[i];
    }
    float inv = 1.f / (den + 1e-16f);
    float scj = sc_s[j];
#pragma unroll
    for (int i = 0; i < 19; i++)
      watt[(j * 8 + h) * 19 + i] = ev[i] * inv * sc_s[i] * scj;
  }
  __syncthreads();
  // ---- gat1 aggregate + bn + skip + gelu -> hb ----
  for (int idx = tid; idx < 19 * 64; idx += 256) {
    int j = idx >> 6, d = idx & 63;
    float acc = 0.f;
#pragma unroll
    for (int h = 0; h < 8; h++) {
      const float* wr = &watt[(j * 8 + h) * 19];
      float a = 0.f;
#pragma unroll
      for (int i = 0; i < 19; i++) a += wr[i] * h1[i * 512 + h * 64 + d];
      acc += a;
    }
    float om = acc * 0.125f + g1bias[d];
    float v = bg1[d] * om + bb1[d];
    float sk = skb[d];
    const float* fr = &fb[j * 32];
#pragma unroll
    for (int c = 0; c < 32; c++) sk += fr[c] * skw[c * 64 + d];
    hb[idx] = geluf(v + sk);
  }
  __syncthreads();

  // ---- h2 = hb(19x64) @ g2w(64x512), overwrite h1 buffer ----
#pragma unroll
  for (int oo = 0; oo < 2; oo++) {
    int o = tid + oo * 256;
    float wc[64];
#pragma unroll
    for (int c = 0; c < 64; c++) wc[c] = g2w[c * 512 + o];
    for (int i = 0; i < 19; i++) {
      float a = 0.f;
#pragma unroll
      for (int c = 0; c < 64; c++) a += hb[i * 64 + c] * wc[c];
      h1[i * 512 + o] = a;
    }
  }
  __syncthreads();

  // ---- gat2 attention ----
  if (tid < 152) {
    int i = tid / 8, h = tid & 7;
    float a = 0.f, d2 = 0.f;
#pragma unroll
    for (int d = 0; d < 64; d++) {
      float hv = h1[i * 512 + h * 64 + d];
      a += hv * g2as[h * 64 + d];
      d2 += hv * g2ad[h * 64 + d];
    }
    as_s[tid] = a;
    ad_s[tid] = d2;
  }
  __syncthreads();
  if (tid < 152) {
    int j = tid / 8, h = tid & 7;
    float adj_ = ad_s[j * 8 + h];
    float ev[19], m = -1e30f;
#pragma unroll
    for (int i = 0; i < 19; i++) {
      float e = lrelu(as_s[i * 8 + h] + adj_);
      ev[i] = e;
      m = fmaxf(m, e);
    }
    float den = 0.f;
#pragma unroll
    for (int i = 0; i < 19; i++) {
      ev[i] = __expf(ev[i] - m);
      den += ev[i];
    }
    float inv = 1.f / (den + 1e-16f);
    float scj = sc_s[j];
#pragma unroll
    for (int i = 0; i < 19; i++)
      watt[(j * 8 + h) * 19 + i] = ev[i] * inv * sc_s[i] * scj;
  }
  __syncthreads();
  // ---- gat2 aggregate + bn + residual + gelu -> hout ----
  for (int idx = tid; idx < 19 * 64; idx += 256) {
    int j = idx >> 6, d = idx & 63;
    float acc = 0.f;
#pragma unroll
    for (int h = 0; h < 8; h++) {
      const float* wr = &watt[(j * 8 + h) * 19];
      float a = 0.f;
#pragma unroll
      for (int i = 0; i < 19; i++) a += wr[i] * h1[i * 512 + h * 64 + d];
      acc += a;
    }
    float om = acc * 0.125f + g2bias[d];
    float v = bg2[d] * om + bb2[d] + om;
    hout[idx] = geluf(v);
  }
  __syncthreads();

  // ---- pool + classifier ----
  if (tid < 64) {
    float a = 0.f;
#pragma unroll
    for (int j = 0; j < 19; j++) a += hout[j * 64 + tid];
    gpool[tid] = a * (1.f / 19.f);
  }
  __syncthreads();
  if (tid < 64) {
    float a = cb1[tid];
#pragma unroll
    for (int d = 0; d < 64; d++) a += gpool[d] * cw1[d * 64 + tid];
    u_s[tid] = geluf(a);
  }
  __syncthreads();
  if (tid < 2) {
    float a = cb2[tid];
#pragma unroll
    for (int e = 0; e < 64; e++) a += u_s[e] * cw2[e * 2 + tid];
    out[b * 2 + tid] = a;
  }
}

// ---------------------------------------------------------------------------
extern "C" void kernel_launch(void* const* d_in, const int* in_sizes, int n_in,
                              void* d_out, int out_size, void* d_ws,
                              size_t ws_size, hipStream_t stream) {
  (void)in_sizes; (void)n_in; (void)out_size; (void)ws_size;
  const float* x = (const float*)d_in[0];
  const float* conv1_w = (const float*)d_in[1];
  const float* bn1_g = (const float*)d_in[2];
  const float* bn1_b = (const float*)d_in[3];
  const float* depth_w = (const float*)d_in[4];
  const float* bn2_g = (const float*)d_in[5];
  const float* bn2_b = (const float*)d_in[6];
  const float* se_w1 = (const float*)d_in[7];
  const float* se_w2 = (const float*)d_in[8];
  const float* sep_w = (const float*)d_in[9];
  const float* bn3_g = (const float*)d_in[10];
  const float* bn3_b = (const float*)d_in[11];
  const float* ms_w0 = (const float*)d_in[12];
  const float* ms_g0 = (const float*)d_in[13];
  const float* ms_b0 = (const float*)d_in[14];
  const float* ms_w1 = (const float*)d_in[15];
  const float* ms_g1 = (const float*)d_in[16];
  const float* ms_b1 = (const float*)d_in[17];
  const float* ms_w2 = (const float*)d_in[18];
  const float* ms_g2 = (const float*)d_in[19];
  const float* ms_b2 = (const float*)d_in[20];
  const float* adj_w = (const float*)d_in[21];
  const float* adj_b = (const float*)d_in[22];
  const float* gat1_w = (const float*)d_in[23];
  const float* gat1_as = (const float*)d_in[24];
  const float* gat1_ad = (const float*)d_in[25];
  const float* gat1_bias = (const float*)d_in[26];
  const float* skip1_w = (const float*)d_in[27];
  const float* skip1_b = (const float*)d_in[28];
  const float* bng1_g = (const float*)d_in[29];
  const float* bng1_b = (const float*)d_in[30];
  const float* gat2_w = (const float*)d_in[31];
  const float* gat2_as = (const float*)d_in[32];
  const float* gat2_ad = (const float*)d_in[33];
  const float* gat2_bias = (const float*)d_in[34];
  const float* bng2_g = (const float*)d_in[35];
  const float* bng2_b = (const float*)d_in[36];
  const float* cls_w1 = (const float*)d_in[37];
  const float* cls_b1 = (const float*)d_in[38];
  const float* cls_w2 = (const float*)d_in[39];
  const float* cls_b2 = (const float*)d_in[40];
  // d_in[41] edge_index / d_in[42] batch_idx: fixed dense structure, unused

  float* ws = (float*)d_ws;
  float* yv = ws;                  // 2,048
  float* feat = ws + 2048;         // 77,824
  float* y4g = ws + 79872;         // 512,000
  float* ssum = ws + 591872;       // 2,048  -> total ~2.3 MB

  hipLaunchKernelGGL(k_pool, dim3(BATCH * 16), dim3(256), 0, stream,
                     x, conv1_w, bn1_g, bn1_b, depth_w, bn2_g, bn2_b, y4g, ssum);
  hipLaunchKernelGGL(k_sep, dim3(BATCH * 16), dim3(256), 0, stream,
                     y4g, ssum, se_w1, se_w2, sep_w, bn3_g, bn3_b, yv);
  hipLaunchKernelGGL(k_ms, dim3(NNODES), dim3(256), 0, stream,
                     x, ms_w0, ms_g0, ms_b0, ms_w1, ms_g1, ms_b1, ms_w2,
                     ms_g2, ms_b2, yv, feat);
  hipLaunchKernelGGL(k_gat, dim3(BATCH), dim3(256), 0, stream,
                     feat, adj_w, adj_b, gat1_w, gat1_as, gat1_ad, gat1_bias,
                     skip1_w, skip1_b, bng1_g, bng1_b, gat2_w, gat2_as,
                     gat2_ad, gat2_bias, bng2_g, bng2_b, cls_w1, cls_b1,
                     cls_w2, cls_b2, (float*)d_out);
}

// Round 12
// 335.777 us; speedup vs baseline: 1.3378x; 1.0288x over previous
//
#include <hip/hip_runtime.h>
#include <hip/hip_bf16.h>
#include <math.h>

#define BATCH 128
#define NCH 19
#define TLEN 1000
#define NNODES (BATCH * NCH)

// fast ELU (k_pool/k_sep/k_gat): negative branch via v_exp_f32.
__device__ __forceinline__ float eluf(float x) { return x > 0.f ? x : __expf(x) - 1.f; }
// r0-exact ELU (k_ms ONLY): expm1f's register pressure shapes the proven
// 80-VGPR schedule; every "cheaper" variant regressed via regalloc.
__device__ __forceinline__ float elu0(float x) { return x > 0.f ? x : expm1f(x); }
__device__ __forceinline__ float geluf(float x) { return 0.5f * x * (1.f + erff(x * 0.70710678118654752f)); }
__device__ __forceinline__ float sigf(float x) { return 1.f / (1.f + __expf(-x)); }
__device__ __forceinline__ float lrelu(float x) { return x > 0.f ? x : 0.2f * x; }

// ---------------------------------------------------------------------------
// K1a: frontend conv stage for one (b,f) pair. (r1-proven, byte-identical)
// grid: B*16 blocks, 256 thr
// ---------------------------------------------------------------------------
__global__ __launch_bounds__(256) void k_pool(
    const float* __restrict__ x, const float* __restrict__ w1,
    const float* __restrict__ bn1g, const float* __restrict__ bn1b,
    const float* __restrict__ dw, const float* __restrict__ bn2g,
    const float* __restrict__ bn2b, float* __restrict__ y4g,
    float* __restrict__ ssum) {
  int blk = blockIdx.x;
  int b = blk >> 4, f = blk & 15;
  int tid = threadIdx.x;
  __shared__ float xw[1024];  // xw[i] = xw_f[i-12], zero-padded
  __shared__ float dws[19], w1s[25];
  __shared__ float redw[4];
  if (tid < 19) dws[tid] = dw[f * 19 + tid];
  else if (tid >= 32 && tid < 57) w1s[tid - 32] = w1[f * 25 + tid - 32];
  __syncthreads();
  const float* xb = x + (size_t)b * NCH * TLEN;
  for (int i = tid; i < 1024; i += 256) {
    int t = i - 12;
    float v = 0.f;
    if (t >= 0 && t < TLEN) {
#pragma unroll
      for (int c = 0; c < 19; c++) v += dws[c] * xb[c * TLEN + t];
    }
    xw[i] = v;
  }
  __syncthreads();
  float g1 = bn1g[f], b1 = bn1b[f];
  float g2 = bn2g[f], b2 = bn2b[f];
  float sumdw = 0.f;
#pragma unroll
  for (int c = 0; c < 19; c++) sumdw += dws[c];
  float scale = g2 * g1, cb = g2 * b1 * sumdw + b2;
  float part = 0.f;
  if (tid < 250) {
    float pool = 0.f;
#pragma unroll
    for (int q = 0; q < 4; q++) {
      int t = 4 * tid + q;
      float acc = 0.f;
#pragma unroll
      for (int k = 0; k < 25; k++) acc += w1s[k] * xw[t + k];
      pool += eluf(scale * acc + cb);
    }
    part = pool;
    y4g[(size_t)(b * 16 + f) * 250 + tid] = pool * 0.25f;
  }
  int lane = tid & 63, wid = tid >> 6;
  for (int off = 32; off > 0; off >>= 1) part += __shfl_down(part, off, 64);
  if (lane == 0) redw[wid] = part;
  __syncthreads();
  if (tid == 0) ssum[b * 16 + f] = redw[0] + redw[1] + redw[2] + redw[3];
}

// ---------------------------------------------------------------------------
// K1b: SE + sep conv (k=16, pad 8) + bn3 + elu + mean -> yv[b,fo] (r1-proven)
// ---------------------------------------------------------------------------
__global__ __launch_bounds__(256) void k_sep(
    const float* __restrict__ y4g, const float* __restrict__ ssum,
    const float* __restrict__ sew1, const float* __restrict__ sew2,
    const float* __restrict__ sw, const float* __restrict__ g3,
    const float* __restrict__ b3, float* __restrict__ yv) {
  int blk = blockIdx.x;
  int b = blk >> 4, fo = blk & 15;
  int tid = threadIdx.x;
  __shared__ float yloc[16 * 268];
  __shared__ float sws[256];
  __shared__ float s_s[16], se_s[16], u4[4];
  __shared__ float redw[4];
  sws[tid] = sw[fo * 256 + tid];
  if (tid < 16) s_s[tid] = ssum[b * 16 + tid] * (1.f / 1000.f);
  __syncthreads();
  if (tid < 4) {
    float a = 0.f;
#pragma unroll
    for (int ff = 0; ff < 16; ff++) a += s_s[ff] * sew1[ff * 4 + tid];
    u4[tid] = geluf(a);
  }
  __syncthreads();
  if (tid < 16) {
    float a = 0.f;
#pragma unroll
    for (int j = 0; j < 4; j++) a += u4[j] * sew2[j * 16 + tid];
    se_s[tid] = sigf(a);
  }
  __syncthreads();
#pragma unroll
  for (int fi = 0; fi < 16; fi++) {
    float sc = se_s[fi];
    const float* yr = y4g + (size_t)(b * 16 + fi) * 250;
    for (int j = tid; j < 268; j += 256) {
      float v = (j >= 8 && j < 258) ? yr[j - 8] * sc : 0.f;
      yloc[fi * 268 + j] = v;
    }
  }
  __syncthreads();
  float accsum = 0.f;
  if (tid < 251) {
    float acc = 0.f;
#pragma unroll
    for (int fi = 0; fi < 16; fi++) {
      const float* yr = &yloc[fi * 268 + tid];
      const float* wp = &sws[fi * 16];
#pragma unroll
      for (int k = 0; k < 16; k++) acc += yr[k] * wp[k];
    }
    accsum = eluf(g3[fo] * acc + b3[fo]);
  }
  int lane = tid & 63, wid = tid >> 6;
  for (int off = 32; off > 0; off >>= 1)
    accsum += __shfl_down(accsum, off, 64);
  if (lane == 0) redw[wid] = accsum;
  __syncthreads();
  if (tid == 0)
    yv[b * 16 + fo] = (redw[0] + redw[1] + redw[2] + redw[3]) * (1.f / 251.f);
}

// ---------------------------------------------------------------------------
// K2: multiscale conv1d — ROUND-0 EXACT (measured 140.9 us, VGPR 80, 0 bank
// conflicts; reproduced r11). DO NOT TOUCH — 10 variants all regressed.
// grid: NNODES blocks, 256 thr.
// ---------------------------------------------------------------------------
#define RP 8
__global__ __launch_bounds__(256) void k_ms(
    const float* __restrict__ x, const float* __restrict__ w0,
    const float* __restrict__ ga0, const float* __restrict__ bb0,
    const float* __restrict__ w1, const float* __restrict__ ga1,
    const float* __restrict__ bb1, const float* __restrict__ w2,
    const float* __restrict__ ga2, const float* __restrict__ bb2,
    const float* __restrict__ yv, float* __restrict__ feat) {
  int n = blockIdx.x, tid = threadIdx.x;
  __shared__ float xr[1034];   // xr[i] = x[n, i-17], zero padded
  __shared__ float wst[1200];  // w0(240) | w1(400) | w2(560)
  __shared__ float red[256];
  for (int i = tid; i < 1034; i += 256) {
    int t = i - 17;
    xr[i] = (t >= 0 && t < TLEN) ? x[(size_t)n * TLEN + t] : 0.f;
  }
  for (int i = tid; i < 240; i += 256) wst[i] = w0[i];
  for (int i = tid; i < 400; i += 256) wst[240 + i] = w1[i];
  for (int i = tid; i < 560; i += 256) wst[640 + i] = w2[i];
  __syncthreads();

  int f = tid & 15, plane = tid >> 4;
  float wa[15], wb[25], wc[35];
#pragma unroll
  for (int k = 0; k < 15; k++) wa[k] = wst[f * 15 + k];
#pragma unroll
  for (int k = 0; k < 25; k++) wb[k] = wst[240 + f * 25 + k];
#pragma unroll
  for (int k = 0; k < 35; k++) wc[k] = wst[640 + f * 35 + k];
  float g0 = ga0[f], c0 = bb0[f];
  float g1 = ga1[f], c1 = bb1[f];
  float g2 = ga2[f], c2 = bb2[f];

  float z = 0.f;
  for (int base = plane * RP; base < TLEN; base += 16 * RP) {
    float xv[34 + RP];
#pragma unroll
    for (int i = 0; i < 34 + RP; i++) xv[i] = xr[base + i];
#pragma unroll
    for (int r = 0; r < RP; r++) {
      float a0 = 0.f, a1 = 0.f, a2 = 0.f;
#pragma unroll
      for (int k = 0; k < 15; k++) a0 += xv[r + 10 + k] * wa[k];
#pragma unroll
      for (int k = 0; k < 25; k++) a1 += xv[r + 5 + k] * wb[k];
#pragma unroll
      for (int k = 0; k < 35; k++) a2 += xv[r + k] * wc[k];
      z += elu0(g0 * a0 + c0) + elu0(g1 * a1 + c1) + elu0(g2 * a2 + c2);
    }
  }
  red[tid] = z;
  __syncthreads();
  for (int s = 128; s >= 16; s >>= 1) {
    if (tid < s) red[tid] += red[tid + s];
    __syncthreads();
  }
  if (tid < 16) {
    feat[(size_t)n * 32 + 16 + tid] = red[tid] * (1.f / 3000.f);
    feat[(size_t)n * 32 + tid] = yv[(n / 19) * 16 + tid];
  }
}

// ---------------------------------------------------------------------------
// K3: fused GAT1 + GAT2 + pool + classifier. NOW 512 THREADS: k_gat was
// 1 wave/SIMD (128 blocks x 256 thr) with all latency exposed; 512 thr gives
// 2 waves/SIMD and halves per-thread h1/h2 work (1 column each).
// grid: B blocks, 512 thr.
// ---------------------------------------------------------------------------
__global__ __launch_bounds__(512) void k_gat(
    const float* __restrict__ feat, const float* __restrict__ adjw,
    const float* __restrict__ adjb, const float* __restrict__ g1w,
    const float* __restrict__ g1as, const float* __restrict__ g1ad,
    const float* __restrict__ g1bias, const float* __restrict__ skw,
    const float* __restrict__ skb, const float* __restrict__ bg1,
    const float* __restrict__ bb1, const float* __restrict__ g2w,
    const float* __restrict__ g2as, const float* __restrict__ g2ad,
    const float* __restrict__ g2bias, const float* __restrict__ bg2,
    const float* __restrict__ bb2, const float* __restrict__ cw1,
    const float* __restrict__ cb1, const float* __restrict__ cw2,
    const float* __restrict__ cb2, float* __restrict__ out) {
  int b = blockIdx.x, tid = threadIdx.x;
  __shared__ float fb[19 * 32];
  __shared__ float h1[19 * 512];  // reused for h2
  __shared__ float as_s[19 * 8], ad_s[19 * 8], sc_s[19];
  __shared__ float watt[19 * 8 * 19];
  __shared__ float hb[19 * 64];   // gat1 output / gat2 input
  __shared__ float hout[19 * 64];
  __shared__ float gpool[64], u_s[64];

  for (int i = tid; i < 19 * 32; i += 512) fb[i] = feat[(size_t)b * 19 * 32 + i];
  __syncthreads();

  // ---- h1 = fb(19x32) @ g1w(32x512): thread owns column tid ----
  {
    float wc0[32];
#pragma unroll
    for (int c = 0; c < 32; c++) wc0[c] = g1w[c * 512 + tid];
    for (int i = 0; i < 19; i++) {
      const float* fr = &fb[i * 32];
      float a0 = 0.f;
#pragma unroll
      for (int c = 0; c < 32; c++) a0 += fr[c] * wc0[c];
      h1[i * 512 + tid] = a0;
    }
  }
  // adjacency scores
  if (tid < 19) {
    float a = adjb[0];
#pragma unroll
    for (int c = 0; c < 32; c++) a += fb[tid * 32 + c] * adjw[c];
    sc_s[tid] = sigf(a);
  }
  __syncthreads();

  // ---- gat1 attention ----
  if (tid < 152) {
    int i = tid / 8, h = tid & 7;
    float a = 0.f, d2 = 0.f;
#pragma unroll
    for (int d = 0; d < 64; d++) {
      float hv = h1[i * 512 + h * 64 + d];
      a += hv * g1as[h * 64 + d];
      d2 += hv * g1ad[h * 64 + d];
    }
    as_s[tid] = a;
    ad_s[tid] = d2;
  }
  __syncthreads();
  if (tid < 152) {
    int j = tid / 8, h = tid & 7;
    float adj_ = ad_s[j * 8 + h];
    float ev[19], m = -1e30f;
#pragma unroll
    for (int i = 0; i < 19; i++) {
      float e = lrelu(as_s[i * 8 + h] + adj_);
      ev[i] = e;
      m = fmaxf(m, e);
    }
    float den = 0.f;
#pragma unroll
    for (int i = 0; i < 19; i++) {
      ev[i] = __expf(ev[i] - m);
      den += ev[i];
    }
    float inv = 1.f / (den + 1e-16f);
    float scj = sc_s[j];
#pragma unroll
    for (int i = 0; i < 19; i++)
      watt[(j * 8 + h) * 19 + i] = ev[i] * inv * sc_s[i] * scj;
  }
  __syncthreads();
  // ---- gat1 aggregate + bn + skip + gelu -> hb ----
  for (int idx = tid; idx < 19 * 64; idx += 512) {
    int j = idx >> 6, d = idx & 63;
    float acc = 0.f;
#pragma unroll
    for (int h = 0; h < 8; h++) {
      const float* wr = &watt[(j * 8 + h) * 19];
      float a = 0.f;
#pragma unroll
      for (int i = 0; i < 19; i++) a += wr[i] * h1[i * 512 + h * 64 + d];
      acc += a;
    }
    float om = acc * 0.125f + g1bias[d];
    float v = bg1[d] * om + bb1[d];
    float sk = skb[d];
    const float* fr = &fb[j * 32];
#pragma unroll
    for (int c = 0; c < 32; c++) sk += fr[c] * skw[c * 64 + d];
    hb[idx] = geluf(v + sk);
  }
  __syncthreads();

  // ---- h2 = hb(19x64) @ g2w(64x512): thread owns column tid ----
  {
    float wc[64];
#pragma unroll
    for (int c = 0; c < 64; c++) wc[c] = g2w[c * 512 + tid];
    for (int i = 0; i < 19; i++) {
      const float* hr = &hb[i * 64];
      float a = 0.f;
#pragma unroll
      for (int c = 0; c < 64; c++) a += hr[c] * wc[c];
      h1[i * 512 + tid] = a;
    }
  }
  __syncthreads();

  // ---- gat2 attention ----
  if (tid < 152) {
    int i = tid / 8, h = tid & 7;
    float a = 0.f, d2 = 0.f;
#pragma unroll
    for (int d = 0; d < 64; d++) {
      float hv = h1[i * 512 + h * 64 + d];
      a += hv * g2as[h * 64 + d];
      d2 += hv * g2ad[h * 64 + d];
    }
    as_s[tid] = a;
    ad_s[tid] = d2;
  }
  __syncthreads();
  if (tid < 152) {
    int j = tid / 8, h = tid & 7;
    float adj_ = ad_s[j * 8 + h];
    float ev[19], m = -1e30f;
#pragma unroll
    for (int i = 0; i < 19; i++) {
      float e = lrelu(as_s[i * 8 + h] + adj_);
      ev[i] = e;
      m = fmaxf(m, e);
    }
    float den = 0.f;
#pragma unroll
    for (int i = 0; i < 19; i++) {
      ev[i] = __expf(ev[i] - m);
      den += ev[i];
    }
    float inv = 1.f / (den + 1e-16f);
    float scj = sc_s[j];
#pragma unroll
    for (int i = 0; i < 19; i++)
      watt[(j * 8 + h) * 19 + i] = ev[i] * inv * sc_s[i] * scj;
  }
  __syncthreads();
  // ---- gat2 aggregate + bn + residual + gelu -> hout ----
  for (int idx = tid; idx < 19 * 64; idx += 512) {
    int j = idx >> 6, d = idx & 63;
    float acc = 0.f;
#pragma unroll
    for (int h = 0; h < 8; h++) {
      const float* wr = &watt[(j * 8 + h) * 19];
      float a = 0.f;
#pragma unroll
      for (int i = 0; i < 19; i++) a += wr[i] * h1[i * 512 + h * 64 + d];
      acc += a;
    }
    float om = acc * 0.125f + g2bias[d];
    float v = bg2[d] * om + bb2[d] + om;
    hout[idx] = geluf(v);
  }
  __syncthreads();

  // ---- pool + classifier ----
  if (tid < 64) {
    float a = 0.f;
#pragma unroll
    for (int j = 0; j < 19; j++) a += hout[j * 64 + tid];
    gpool[tid] = a * (1.f / 19.f);
  }
  __syncthreads();
  if (tid < 64) {
    float a = cb1[tid];
#pragma unroll
    for (int d = 0; d < 64; d++) a += gpool[d] * cw1[d * 64 + tid];
    u_s[tid] = geluf(a);
  }
  __syncthreads();
  if (tid < 2) {
    float a = cb2[tid];
#pragma unroll
    for (int e = 0; e < 64; e++) a += u_s[e] * cw2[e * 2 + tid];
    out[b * 2 + tid] = a;
  }
}

// ---------------------------------------------------------------------------
extern "C" void kernel_launch(void* const* d_in, const int* in_sizes, int n_in,
                              void* d_out, int out_size, void* d_ws,
                              size_t ws_size, hipStream_t stream) {
  (void)in_sizes; (void)n_in; (void)out_size; (void)ws_size;
  const float* x = (const float*)d_in[0];
  const float* conv1_w = (const float*)d_in[1];
  const float* bn1_g = (const float*)d_in[2];
  const float* bn1_b = (const float*)d_in[3];
  const float* depth_w = (const float*)d_in[4];
  const float* bn2_g = (const float*)d_in[5];
  const float* bn2_b = (const float*)d_in[6];
  const float* se_w1 = (const float*)d_in[7];
  const float* se_w2 = (const float*)d_in[8];
  const float* sep_w = (const float*)d_in[9];
  const float* bn3_g = (const float*)d_in[10];
  const float* bn3_b = (const float*)d_in[11];
  const float* ms_w0 = (const float*)d_in[12];
  const float* ms_g0 = (const float*)d_in[13];
  const float* ms_b0 = (const float*)d_in[14];
  const float* ms_w1 = (const float*)d_in[15];
  const float* ms_g1 = (const float*)d_in[16];
  const float* ms_b1 = (const float*)d_in[17];
  const float* ms_w2 = (const float*)d_in[18];
  const float* ms_g2 = (const float*)d_in[19];
  const float* ms_b2 = (const float*)d_in[20];
  const float* adj_w = (const float*)d_in[21];
  const float* adj_b = (const float*)d_in[22];
  const float* gat1_w = (const float*)d_in[23];
  const float* gat1_as = (const float*)d_in[24];
  const float* gat1_ad = (const float*)d_in[25];
  const float* gat1_bias = (const float*)d_in[26];
  const float* skip1_w = (const float*)d_in[27];
  const float* skip1_b = (const float*)d_in[28];
  const float* bng1_g = (const float*)d_in[29];
  const float* bng1_b = (const float*)d_in[30];
  const float* gat2_w = (const float*)d_in[31];
  const float* gat2_as = (const float*)d_in[32];
  const float* gat2_ad = (const float*)d_in[33];
  const float* gat2_bias = (const float*)d_in[34];
  const float* bng2_g = (const float*)d_in[35];
  const float* bng2_b = (const float*)d_in[36];
  const float* cls_w1 = (const float*)d_in[37];
  const float* cls_b1 = (const float*)d_in[38];
  const float* cls_w2 = (const float*)d_in[39];
  const float* cls_b2 = (const float*)d_in[40];
  // d_in[41] edge_index / d_in[42] batch_idx: fixed dense structure, unused

  float* ws = (float*)d_ws;
  float* yv = ws;                  // 2,048
  float* feat = ws + 2048;         // 77,824
  float* y4g = ws + 79872;         // 512,000
  float* ssum = ws + 591872;       // 2,048  -> total ~2.3 MB

  hipLaunchKernelGGL(k_pool, dim3(BATCH * 16), dim3(256), 0, stream,
                     x, conv1_w, bn1_g, bn1_b, depth_w, bn2_g, bn2_b, y4g, ssum);
  hipLaunchKernelGGL(k_sep, dim3(BATCH * 16), dim3(256), 0, stream,
                     y4g, ssum, se_w1, se_w2, sep_w, bn3_g, bn3_b, yv);
  hipLaunchKernelGGL(k_ms, dim3(NNODES), dim3(256), 0, stream,
                     x, ms_w0, ms_g0, ms_b0, ms_w1, ms_g1, ms_b1, ms_w2,
                     ms_g2, ms_b2, yv, feat);
  hipLaunchKernelGGL(k_gat, dim3(BATCH), dim3(512), 0, stream,
                     feat, adj_w, adj_b, gat1_w, gat1_as, gat1_ad, gat1_bias,
                     skip1_w, skip1_b, bng1_g, bng1_b, gat2_w, gat2_as,
                     gat2_ad, gat2_bias, bng2_g, bng2_b, cls_w1, cls_b1,
                     cls_w2, cls_b2, (float*)d_out);
}